// Round 14
// baseline (949.858 us; speedup 1.0000x reference)
//
#include <hip/hip_runtime.h>

#define NN 30000
#define EE 480000
#define HH 256
#define TT 4
#define GG 64
#define CC 10
#define MP 30080   // 235 * 128, padded rows
#define SCAN_B 30  // ceil(NN/1024)
#define STB 120    // stats blocks
#define KU 1088    // u row stride: 4*256 etype sums + 4 counts + 60 zero pad

typedef unsigned short u16;
typedef unsigned int u32;
typedef _Float16 f16;
typedef f16 half8 __attribute__((ext_vector_type(8)));
typedef f16 half4 __attribute__((ext_vector_type(4)));
typedef float f32x4 __attribute__((ext_vector_type(4)));

// ---------- helpers ----------
__device__ __forceinline__ u32 encf(float x) {       // order-preserving float->uint
    u32 u = __float_as_uint(x);
    return (u & 0x80000000u) ? ~u : (u | 0x80000000u);
}
__device__ __forceinline__ float decf(u32 e) {
    u32 u = (e & 0x80000000u) ? (e ^ 0x80000000u) : ~e;
    return __uint_as_float(u);
}
__device__ __forceinline__ void gl_lds16(const void* g, void* l) {
    __builtin_amdgcn_global_load_lds(
        (const __attribute__((address_space(1))) void*)g,
        (__attribute__((address_space(3))) void*)l, 16, 0, 0);
}
// XCD-aware swizzle for 8-col-tile grids (1880 blocks), verified win R11.
__device__ __forceinline__ void xcd_map(int L, int& m0, int& col) {
    int idx = (L & 7) * 235 + (L >> 3);
    m0 = (idx >> 3) * 128;
    col = idx & 7;
}

// ---------- conversion / packing kernels ----------
// Wcat [256 rows k][KU cols]: cols t*256+h = W_msg[t][k][h]; cols 1024+t = b_msg[t][k]; rest 0
__global__ void k_pack_W(const float* __restrict__ W_msg, const float* __restrict__ b_msg,
                         f16* __restrict__ o) {
    int i = blockIdx.x * 256 + threadIdx.x;   // over 256*KU
    if (i >= 256 * KU) return;
    int k = i / KU, j = i % KU;
    float v;
    if (j < 1024) { int t = j >> 8, hh = j & 255; v = W_msg[((t << 8) + k) * 256 + hh]; }
    else if (j < 1028) v = b_msg[(j - 1024) * 256 + k];
    else v = 0.f;
    o[i] = (f16)v;
}

// fused-GRU weight wP [8 groups][128 rows][512] (verified R13):
// group g rows: [0,32)=r (K full), [32,64)=i_n (K<256), [64,96)=z (K full), [96,128)=h_n (K>=256)
__global__ void k_pack_P(const float* __restrict__ w_ih, const float* __restrict__ w_hh,
                         f16* __restrict__ o) {
    int i = blockIdx.x * 256 + threadIdx.x;   // over 1024*512
    int p = i >> 9, k = i & 511;
    int g = p >> 7, t = p & 127;
    float v;
    if (t < 32) {
        int row = g * 32 + t;
        v = (k < 256) ? w_ih[row * 256 + k] : w_hh[row * 256 + (k - 256)];
    } else if (t < 64) {
        int row = 512 + g * 32 + (t - 32);
        v = (k < 256) ? w_ih[row * 256 + k] : 0.f;
    } else if (t < 96) {
        int row = 256 + g * 32 + (t - 64);
        v = (k < 256) ? w_ih[row * 256 + k] : w_hh[row * 256 + (k - 256)];
    } else {
        int row = 512 + g * 32 + (t - 96);
        v = (k >= 256) ? w_hh[row * 256 + (k - 256)] : 0.f;
    }
    o[i] = (f16)v;
}

__global__ void k_biasP(const float* __restrict__ b_ih, const float* __restrict__ b_hh,
                        float* __restrict__ bP) {
    int p = threadIdx.x + blockIdx.x * 256;
    if (p >= 1024) return;
    int g = p >> 7, t = p & 127;
    float v;
    if (t < 32)       { int r = g * 32 + t;            v = b_ih[r] + b_hh[r]; }
    else if (t < 64)  { int r = 512 + g * 32 + t - 32; v = b_ih[r]; }
    else if (t < 96)  { int r = 256 + g * 32 + t - 64; v = b_ih[r] + b_hh[r]; }
    else              { int r = 512 + g * 32 + t - 96; v = b_hh[r]; }
    bP[p] = v;
}

// h state -> ah cols 256..511. Padded rows = 0.
__global__ __launch_bounds__(256) void k_feat(const float* __restrict__ feat,
                                              f16* __restrict__ ah) {
    int n = blockIdx.x, c = threadIdx.x;
    float v = (n < NN) ? feat[(size_t)n * HH + c] : 0.f;
    ah[(size_t)n * 512 + 256 + c] = (f16)v;
}

// ---------- CSR build ----------
__global__ void k_count(const int* __restrict__ dst, int* __restrict__ cnt) {
    int e = blockIdx.x * 256 + threadIdx.x;
    if (e < EE) atomicAdd(&cnt[dst[e]], 1);
}

__global__ __launch_bounds__(1024) void k_scan1(const int* __restrict__ cnt,
                                                int* __restrict__ rowptr,
                                                int* __restrict__ bsum) {
    __shared__ int buf[1024];
    int b = blockIdx.x, tid = threadIdx.x;
    int idx = b * 1024 + tid;
    int x = (idx < NN) ? cnt[idx] : 0;
    buf[tid] = x;
    __syncthreads();
    for (int ofs = 1; ofs < 1024; ofs <<= 1) {
        int v = (tid >= ofs) ? buf[tid - ofs] : 0;
        __syncthreads();
        buf[tid] += v;
        __syncthreads();
    }
    if (idx < NN) rowptr[idx] = buf[tid] - x;
    if (tid == 1023) bsum[b] = buf[1023];
}

__global__ void k_scan2(int* __restrict__ bsum) {
    __shared__ int s[SCAN_B];
    int tid = threadIdx.x;
    if (tid < SCAN_B) s[tid] = bsum[tid];
    __syncthreads();
    if (tid == 0) {
        int run = 0;
        for (int i = 0; i < SCAN_B; ++i) { int v = s[i]; s[i] = run; run += v; }
    }
    __syncthreads();
    if (tid < SCAN_B) bsum[tid] = s[tid];
}

__global__ __launch_bounds__(1024) void k_scan3(int* __restrict__ rowptr,
                                                const int* __restrict__ bsum,
                                                int* __restrict__ cur) {
    int b = blockIdx.x, tid = threadIdx.x;
    int idx = b * 1024 + tid;
    if (idx < NN) {
        int v = rowptr[idx] + bsum[b];
        rowptr[idx] = v;
        cur[idx] = v;
    }
    if (idx == 0) rowptr[NN] = EE;
}

__global__ void k_fill(const int* __restrict__ src, const int* __restrict__ dst,
                       const int* __restrict__ et, int* __restrict__ cur,
                       int* __restrict__ colpk) {
    int e = blockIdx.x * 256 + threadIdx.x;
    if (e < EE) {
        int pos = atomicAdd(&cur[dst[e]], 1);
        colpk[pos] = (et[e] << 16) | src[e];
    }
}

// ---------- per-etype h aggregation: u[n] = [S_0|S_1|S_2|S_3|cnt|0pad] ----------
// Block per node, 4 waves (strips) x 64 lanes (4 cols each). Wave-uniform etype.
__global__ __launch_bounds__(256) void k_aggh(const f16* __restrict__ ah,
                                              const int* __restrict__ rowptr,
                                              const int* __restrict__ colpk,
                                              f16* __restrict__ u) {
    __shared__ int spk[256];
    __shared__ float4 sacc[3][4][64];
    __shared__ int scnt[4][4];
    const int n = blockIdx.x;
    const int tid = threadIdx.x;
    const int col4 = tid & 63;
    const int strip = tid >> 6;
    float4 a0 = {0,0,0,0}, a1 = {0,0,0,0}, a2 = {0,0,0,0}, a3 = {0,0,0,0};
    int c0 = 0, c1 = 0, c2 = 0, c3 = 0;

    if (n < NN) {
        const int e0 = rowptr[n], e1 = rowptr[n + 1];
        for (int base = e0; base < e1; base += 256) {
            const int chunk = min(256, e1 - base);
            __syncthreads();
            if (tid < chunk) spk[tid] = colpk[base + tid];
            __syncthreads();
            for (int i = strip; i < chunk; i += 4) {
                const int pk = spk[i];
                const half4 v = *(const half4*)&ah[(size_t)(pk & 0xFFFF) * 512 + 256 + col4 * 4];
                const int t = pk >> 16;            // wave-uniform
                if (t == 0)      { a0.x += (float)v.x; a0.y += (float)v.y; a0.z += (float)v.z; a0.w += (float)v.w; c0++; }
                else if (t == 1) { a1.x += (float)v.x; a1.y += (float)v.y; a1.z += (float)v.z; a1.w += (float)v.w; c1++; }
                else if (t == 2) { a2.x += (float)v.x; a2.y += (float)v.y; a2.z += (float)v.z; a2.w += (float)v.w; c2++; }
                else             { a3.x += (float)v.x; a3.y += (float)v.y; a3.z += (float)v.z; a3.w += (float)v.w; c3++; }
            }
        }
    }
    if (strip) {
        sacc[strip - 1][0][col4] = a0;
        sacc[strip - 1][1][col4] = a1;
        sacc[strip - 1][2][col4] = a2;
        sacc[strip - 1][3][col4] = a3;
        if (col4 == 0) { scnt[strip][0] = c0; scnt[strip][1] = c1; scnt[strip][2] = c2; scnt[strip][3] = c3; }
    } else if (col4 == 0) {
        scnt[0][0] = c0; scnt[0][1] = c1; scnt[0][2] = c2; scnt[0][3] = c3;
    }
    __syncthreads();
    if (strip == 0 && n < NN) {
#pragma unroll
        for (int s2 = 0; s2 < 3; ++s2) {
            float4 t;
            t = sacc[s2][0][col4]; a0.x += t.x; a0.y += t.y; a0.z += t.z; a0.w += t.w;
            t = sacc[s2][1][col4]; a1.x += t.x; a1.y += t.y; a1.z += t.z; a1.w += t.w;
            t = sacc[s2][2][col4]; a2.x += t.x; a2.y += t.y; a2.z += t.z; a2.w += t.w;
            t = sacc[s2][3][col4]; a3.x += t.x; a3.y += t.y; a3.z += t.z; a3.w += t.w;
        }
        f16* ur = u + (size_t)n * KU;
        half4 o;
        o.x = (f16)a0.x; o.y = (f16)a0.y; o.z = (f16)a0.z; o.w = (f16)a0.w;
        *(half4*)&ur[0 * 256 + col4 * 4] = o;
        o.x = (f16)a1.x; o.y = (f16)a1.y; o.z = (f16)a1.z; o.w = (f16)a1.w;
        *(half4*)&ur[1 * 256 + col4 * 4] = o;
        o.x = (f16)a2.x; o.y = (f16)a2.y; o.z = (f16)a2.z; o.w = (f16)a2.w;
        *(half4*)&ur[2 * 256 + col4 * 4] = o;
        o.x = (f16)a3.x; o.y = (f16)a3.y; o.z = (f16)a3.z; o.w = (f16)a3.w;
        *(half4*)&ur[3 * 256 + col4 * 4] = o;
        if (col4 < 16) {
            float vals[4];
#pragma unroll
            for (int r = 0; r < 4; ++r) {
                int c = col4 * 4 + r;
                vals[r] = (c < 4) ? (float)(scnt[0][c] + scnt[1][c] + scnt[2][c] + scnt[3][c]) : 0.f;
            }
            half4 cv;
            cv.x = (f16)vals[0]; cv.y = (f16)vals[1]; cv.z = (f16)vals[2]; cv.w = (f16)vals[3];
            *(half4*)&ur[1024 + col4 * 4] = cv;
        }
    }
}

// ---------- a-GEMM: a[MP x 256] = u[MP x KU] * Wcat[256 x KU]^T  (writes ah cols 0..255) ----------
// 472 blocks: idx=(L&7)*59+(L>>3); row=idx>>1, col=idx&1; guard row<235.
__global__ __launch_bounds__(256) void gemm_a(
    const f16* __restrict__ A,
    const f16* __restrict__ B,
    f16* __restrict__ C) {
    __shared__ f16 sA[8192], sB[8192];
    const int tid = threadIdx.x;
    const int lane = tid & 63;
    const int wv = tid >> 6;
    const int wr = wv >> 1, wc = wv & 1;
    const int idx = (blockIdx.x & 7) * 59 + (blockIdx.x >> 3);
    const int m0 = (idx >> 1) * 128;
    if (m0 >= MP) return;
    const int n0 = (idx & 1) * 128;

    const int ldRow = tid >> 3;
    const int ldK = ((tid & 7) ^ (ldRow & 7)) * 8;
    const f16* aP = A + (size_t)(m0 + ldRow) * KU + ldK;
    const f16* bP = B + (size_t)(n0 + ldRow) * KU + ldK;
    const size_t rstepA = (size_t)32 * KU;
    const size_t rstepB = (size_t)32 * KU;

    const int wbyte = (tid & ~63) * 16;
    char* dA = (char*)sA + wbyte;
    char* dB = (char*)sB + wbyte;

    f32x4 acc[4][4];
#pragma unroll
    for (int i = 0; i < 4; i++)
#pragma unroll
        for (int j = 0; j < 4; j++) acc[i][j] = {0.f, 0.f, 0.f, 0.f};

    const int fr = lane & 15;
    const int l7 = lane & 7;
    const int cq = lane >> 4;
    const int p0 = (cq ^ l7) * 8;
    const int p1 = ((cq + 4) ^ l7) * 8;

    for (int kt = 0; kt < 17; ++kt) {
        const int k0 = kt * 64;
        __syncthreads();
        gl_lds16(aP + k0, dA);
        gl_lds16(aP + k0 + rstepA, dA + 4096);
        gl_lds16(aP + k0 + 2 * rstepA, dA + 8192);
        gl_lds16(aP + k0 + 3 * rstepA, dA + 12288);
        gl_lds16(bP + k0, dB);
        gl_lds16(bP + k0 + rstepB, dB + 4096);
        gl_lds16(bP + k0 + 2 * rstepB, dB + 8192);
        gl_lds16(bP + k0 + 3 * rstepB, dB + 12288);
        __syncthreads();

#pragma unroll
        for (int kk = 0; kk < 2; ++kk) {
            const int p = kk ? p1 : p0;
            half8 bh[4];
#pragma unroll
            for (int j = 0; j < 4; j++) {
                int brow = wc * 64 + j * 16 + fr;
                bh[j] = *(const half8*)&sB[brow * 64 + p];
            }
#pragma unroll
            for (int i = 0; i < 4; i++) {
                int arow = wr * 64 + i * 16 + fr;
                half8 av = *(const half8*)&sA[arow * 64 + p];
#pragma unroll
                for (int j = 0; j < 4; j++)
                    acc[i][j] = __builtin_amdgcn_mfma_f32_16x16x32_f16(av, bh[j], acc[i][j], 0, 0, 0);
            }
        }
    }

    const int lr = (lane >> 4) * 4;
    const int lc = lane & 15;
#pragma unroll
    for (int j = 0; j < 4; j++) {
        const int col = n0 + wc * 64 + j * 16 + lc;   // 0..255 -> a cols of ah
#pragma unroll
        for (int i = 0; i < 4; i++) {
            const int rb = m0 + wr * 64 + i * 16 + lr;
#pragma unroll
            for (int r = 0; r < 4; r++)
                C[(size_t)(rb + r) * 512 + col] = (f16)acc[i][j][r];
        }
    }
}

// ---------- fused GRU GEMM+cell, exchange-free (verified R13) ----------
__global__ __launch_bounds__(256) void gemm_gruf(
    const f16* __restrict__ ahCur,
    const f16* __restrict__ wP,
    const float* __restrict__ bias,
    f16* __restrict__ ahNxt) {
    __shared__ f16 sA[8192], sB[8192];
    const int tid = threadIdx.x;
    const int lane = tid & 63;
    const int wv = tid >> 6;
    int m0, grp;
    xcd_map(blockIdx.x, m0, grp);
    const int n0 = grp * 128;
    const int gcol = grp * 32;

    const int ldRow = tid >> 3;
    const int ldK = ((tid & 7) ^ (ldRow & 7)) * 8;
    const f16* aP = ahCur + (size_t)(m0 + ldRow) * 512 + ldK;
    const f16* bPp = wP + (size_t)(n0 + ldRow) * 512 + ldK;
    const size_t rstep = (size_t)32 * 512;

    const int wbyte = (tid & ~63) * 16;
    char* dA = (char*)sA + wbyte;
    char* dB = (char*)sB + wbyte;

    f32x4 acc[2][8];
#pragma unroll
    for (int i = 0; i < 2; i++)
#pragma unroll
        for (int j = 0; j < 8; j++) acc[i][j] = {0.f, 0.f, 0.f, 0.f};

    const int fr = lane & 15;
    const int l7 = lane & 7;
    const int cq = lane >> 4;
    const int p0 = (cq ^ l7) * 8;
    const int p1 = ((cq + 4) ^ l7) * 8;

#pragma unroll
    for (int hf = 0; hf < 2; ++hf) {
        const int je = hf ? 6 : 2;
#pragma unroll 1
        for (int kt2 = 0; kt2 < 4; ++kt2) {
            const int k0 = (hf * 4 + kt2) * 64;
            __syncthreads();
            gl_lds16(aP + k0, dA);
            gl_lds16(aP + k0 + rstep, dA + 4096);
            gl_lds16(aP + k0 + 2 * rstep, dA + 8192);
            gl_lds16(aP + k0 + 3 * rstep, dA + 12288);
            gl_lds16(bPp + k0, dB);
            gl_lds16(bPp + k0 + rstep, dB + 4096);
            gl_lds16(bPp + k0 + 2 * rstep, dB + 8192);
            gl_lds16(bPp + k0 + 3 * rstep, dB + 12288);
            __syncthreads();

#pragma unroll
            for (int kk = 0; kk < 2; ++kk) {
                const int p = kk ? p1 : p0;
                const half8 a0 = *(const half8*)&sA[(wv * 32 + fr) * 64 + p];
                const half8 a1 = *(const half8*)&sA[(wv * 32 + 16 + fr) * 64 + p];
                half8 b;
                b = *(const half8*)&sB[(0 * 16 + fr) * 64 + p];
                acc[0][0] = __builtin_amdgcn_mfma_f32_16x16x32_f16(a0, b, acc[0][0], 0, 0, 0);
                acc[1][0] = __builtin_amdgcn_mfma_f32_16x16x32_f16(a1, b, acc[1][0], 0, 0, 0);
                b = *(const half8*)&sB[(1 * 16 + fr) * 64 + p];
                acc[0][1] = __builtin_amdgcn_mfma_f32_16x16x32_f16(a0, b, acc[0][1], 0, 0, 0);
                acc[1][1] = __builtin_amdgcn_mfma_f32_16x16x32_f16(a1, b, acc[1][1], 0, 0, 0);
                b = *(const half8*)&sB[(4 * 16 + fr) * 64 + p];
                acc[0][4] = __builtin_amdgcn_mfma_f32_16x16x32_f16(a0, b, acc[0][4], 0, 0, 0);
                acc[1][4] = __builtin_amdgcn_mfma_f32_16x16x32_f16(a1, b, acc[1][4], 0, 0, 0);
                b = *(const half8*)&sB[(5 * 16 + fr) * 64 + p];
                acc[0][5] = __builtin_amdgcn_mfma_f32_16x16x32_f16(a0, b, acc[0][5], 0, 0, 0);
                acc[1][5] = __builtin_amdgcn_mfma_f32_16x16x32_f16(a1, b, acc[1][5], 0, 0, 0);
                b = *(const half8*)&sB[(je * 16 + fr) * 64 + p];
                acc[0][je] = __builtin_amdgcn_mfma_f32_16x16x32_f16(a0, b, acc[0][je], 0, 0, 0);
                acc[1][je] = __builtin_amdgcn_mfma_f32_16x16x32_f16(a1, b, acc[1][je], 0, 0, 0);
                b = *(const half8*)&sB[((je + 1) * 16 + fr) * 64 + p];
                acc[0][je + 1] = __builtin_amdgcn_mfma_f32_16x16x32_f16(a0, b, acc[0][je + 1], 0, 0, 0);
                acc[1][je + 1] = __builtin_amdgcn_mfma_f32_16x16x32_f16(a1, b, acc[1][je + 1], 0, 0, 0);
            }
        }
    }

    const int lr = (lane >> 4) * 4;
    const int lc = lane & 15;
#pragma unroll
    for (int jj = 0; jj < 2; ++jj) {
        const int c32 = jj * 16 + lc;
        const float br = bias[n0 + c32];
        const float bi = bias[n0 + 32 + c32];
        const float bz = bias[n0 + 64 + c32];
        const float bn = bias[n0 + 96 + c32];
#pragma unroll
        for (int i = 0; i < 2; ++i) {
#pragma unroll
            for (int r = 0; r < 4; ++r) {
                const int n = m0 + wv * 32 + i * 16 + lr + r;
                float rv = acc[i][jj][r] + br;
                float iv = acc[i][jj + 2][r] + bi;
                float zv = acc[i][jj + 4][r] + bz;
                float nv = acc[i][jj + 6][r] + bn;
                float rr = 1.f / (1.f + expf(-rv));
                float zz = 1.f / (1.f + expf(-zv));
                float nn2 = tanhf(iv + rr * nv);
                size_t hidx = (size_t)n * 512 + 256 + gcol + c32;
                float hv = (float)ahCur[hidx];
                ahNxt[hidx] = (f16)((1.f - zz) * nn2 + zz * hv);
            }
        }
    }
}

// ---------- BN stats over elu(h): per-block partials, NO atomics ----------
__global__ __launch_bounds__(256) void k_stats(const f16* __restrict__ ah,
                                               float* __restrict__ pbuf) {
    __shared__ float4 ssum[3][64], ssq[3][64];
    int tid = threadIdx.x, lane = tid & 63, w = tid >> 6;
    int c4 = lane * 4;
    float4 s = {0.f, 0.f, 0.f, 0.f}, q = {0.f, 0.f, 0.f, 0.f};
    for (int n = blockIdx.x * 4 + w; n < NN; n += STB * 4) {
        half4 v = *(const half4*)&ah[(size_t)n * 512 + 256 + c4];
        float ex = (float)v.x, ey = (float)v.y, ez = (float)v.z, ew = (float)v.w;
        ex = ex > 0.f ? ex : expm1f(ex);
        ey = ey > 0.f ? ey : expm1f(ey);
        ez = ez > 0.f ? ez : expm1f(ez);
        ew = ew > 0.f ? ew : expm1f(ew);
        s.x += ex; s.y += ey; s.z += ez; s.w += ew;
        q.x += ex * ex; q.y += ey * ey; q.z += ez * ez; q.w += ew * ew;
    }
    if (w) { ssum[w - 1][lane] = s; ssq[w - 1][lane] = q; }
    __syncthreads();
    if (w == 0) {
#pragma unroll
        for (int k = 0; k < 3; ++k) {
            float4 a = ssum[k][lane], b = ssq[k][lane];
            s.x += a.x; s.y += a.y; s.z += a.z; s.w += a.w;
            q.x += b.x; q.y += b.y; q.z += b.z; q.w += b.w;
        }
        *(float4*)&pbuf[blockIdx.x * 512 + c4] = s;
        *(float4*)&pbuf[blockIdx.x * 512 + 256 + c4] = q;
    }
}

// ---------- reduce partials + fold BN affine into gate weights ----------
__global__ __launch_bounds__(256) void k_prep(const float* __restrict__ pbuf,
                                              const float* __restrict__ gamma,
                                              const float* __restrict__ beta,
                                              const float* __restrict__ gate_w,
                                              const float* __restrict__ gate_b,
                                              float* __restrict__ wp,
                                              float* __restrict__ bnsum,
                                              float* __restrict__ bnsq) {
    __shared__ float red[256];
    int c = threadIdx.x;
    float s = 0.f, q = 0.f;
    for (int b = 0; b < STB; ++b) {
        s += pbuf[b * 512 + c];
        q += pbuf[b * 512 + 256 + c];
    }
    bnsum[c] = s;
    bnsq[c] = q;
    float mu = s * (1.f / NN);
    float var = q * (1.f / NN) - mu * mu;
    float rs = rsqrtf(var + 1e-5f);
    float gm = gamma[c], w = gate_w[c];
    wp[c] = rs * gm * w;
    red[c] = (beta[c] - mu * rs * gm) * w;
    __syncthreads();
    for (int st = 128; st > 0; st >>= 1) {
        if (c < st) red[c] += red[c + st];
        __syncthreads();
    }
    if (c == 0) wp[256] = red[0] + gate_b[0];
}

// ---------- gate score: elu on the fly, wave dots, LDS-staged segment max ----------
__global__ __launch_bounds__(256) void k_gate(const f16* __restrict__ ah,
                                              const float* __restrict__ wp,
                                              const int* __restrict__ n2g,
                                              float* __restrict__ gate,
                                              u32* __restrict__ gmaxenc) {
    __shared__ u32 smax[64];
    int tid = threadIdx.x;
    if (tid < 64) smax[tid] = 0;
    __syncthreads();
    int lane = tid & 63, wv = tid >> 6;
    int base = blockIdx.x * 128 + wv * 32;
    float4 w = ((const float4*)wp)[lane];
    float wc = wp[256];
    for (int k = 0; k < 32; ++k) {
        int n = base + k;
        if (n >= NN) break;
        half4 v = *(const half4*)&ah[(size_t)n * 512 + 256 + lane * 4];
        float ex = (float)v.x, ey = (float)v.y, ez = (float)v.z, ew = (float)v.w;
        ex = ex > 0.f ? ex : expm1f(ex);
        ey = ey > 0.f ? ey : expm1f(ey);
        ez = ez > 0.f ? ez : expm1f(ez);
        ew = ew > 0.f ? ew : expm1f(ew);
        float s = ex * w.x + ey * w.y + ez * w.z + ew * w.w;
#pragma unroll
        for (int off = 32; off; off >>= 1) s += __shfl_down(s, off);
        if (lane == 0) {
            float gt = s + wc;
            gate[n] = gt;
            atomicMax(&smax[n2g[n]], encf(gt));
        }
    }
    __syncthreads();
    if (tid < 64 && smax[tid]) atomicMax(&gmaxenc[tid], smax[tid]);
}

// ---------- exp + denom (LDS-staged segment sum) ----------
__global__ void k_expden(float* __restrict__ gate,
                         const int* __restrict__ n2g,
                         const u32* __restrict__ gmaxenc,
                         float* __restrict__ denom) {
    __shared__ float ssum[64];
    int tid = threadIdx.x;
    if (tid < 64) ssum[tid] = 0.f;
    __syncthreads();
    int n = blockIdx.x * 256 + tid;
    if (n < NN) {
        int g = n2g[n];
        float e = expf(gate[n] - decf(gmaxenc[g]));
        gate[n] = e;
        atomicAdd(&ssum[g], e);
    }
    __syncthreads();
    if (tid < 64 && ssum[tid] != 0.f) atomicAdd(&denom[tid], ssum[tid]);
}

// ---------- attention pooling, elu on the fly (n2g sorted; flush on change) ----------
__global__ __launch_bounds__(256) void k_pool(const f16* __restrict__ ah,
                                              const float* __restrict__ gate,
                                              const float* __restrict__ denom,
                                              const int* __restrict__ n2g,
                                              float* __restrict__ h_g) {
    int c = threadIdx.x;
    int r0 = blockIdx.x * 32, r1 = min(r0 + 32, NN);
    int gcur = -1;
    float accv = 0.f, inv = 0.f;
    for (int n = r0; n < r1; ++n) {
        int g = n2g[n];
        if (g != gcur) {
            if (gcur >= 0) atomicAdd(&h_g[gcur * HH + c], accv);
            gcur = g;
            accv = 0.f;
            inv = 1.f / denom[g];
        }
        float x = (float)ah[(size_t)n * 512 + 256 + c];
        x = x > 0.f ? x : expm1f(x);
        accv += gate[n] * inv * x;
    }
    if (gcur >= 0) atomicAdd(&h_g[gcur * HH + c], accv);
}

// ---------- classifier (applies BN affine to pooled vector) ----------
__global__ __launch_bounds__(256) void k_cls(const float* __restrict__ h_g,
                                             const float* __restrict__ bnsum,
                                             const float* __restrict__ bnsq,
                                             const float* __restrict__ gamma,
                                             const float* __restrict__ beta,
                                             const float* __restrict__ W1,
                                             const float* __restrict__ b1,
                                             const float* __restrict__ W2,
                                             const float* __restrict__ b2,
                                             float* __restrict__ out) {
    __shared__ float hg[256];
    __shared__ float x1[128];
    int g = blockIdx.x, tid = threadIdx.x;
    float mu = bnsum[tid] * (1.f / NN);
    float var = bnsq[tid] * (1.f / NN) - mu * mu;
    hg[tid] = (h_g[g * HH + tid] - mu) * rsqrtf(var + 1e-5f) * gamma[tid] + beta[tid];
    __syncthreads();
    if (tid < 128) {
        const float* w = W1 + tid * 256;
        float s = b1[tid];
#pragma unroll 8
        for (int c = 0; c < 256; ++c) s += hg[c] * w[c];
        x1[tid] = fmaxf(s, 0.f);
    }
    __syncthreads();
    if (tid < 10) {
        const float* w = W2 + tid * 128;
        float s = b2[tid];
        for (int j = 0; j < 128; ++j) s += x1[j] * w[j];
        out[g * CC + tid] = s;
    }
}

// =======================================================================
extern "C" void kernel_launch(void* const* d_in, const int* in_sizes, int n_in,
                              void* d_out, int out_size, void* d_ws, size_t ws_size,
                              hipStream_t stream) {
    const float* feat  = (const float*)d_in[0];
    const int*   src   = (const int*)d_in[1];
    const int*   dst   = (const int*)d_in[2];
    const int*   etype = (const int*)d_in[3];
    const int*   n2g   = (const int*)d_in[4];
    const float* W_msg = (const float*)d_in[5];
    const float* b_msg = (const float*)d_in[6];
    const float* w_ih  = (const float*)d_in[7];
    const float* w_hh  = (const float*)d_in[8];
    const float* b_ih  = (const float*)d_in[9];
    const float* b_hh  = (const float*)d_in[10];
    const float* bn_g  = (const float*)d_in[11];
    const float* bn_b  = (const float*)d_in[12];
    const float* gatew = (const float*)d_in[13];
    const float* gateb = (const float*)d_in[14];
    const float* W1    = (const float*)d_in[15];
    const float* b1    = (const float*)d_in[16];
    const float* W2    = (const float*)d_in[17];
    const float* b2    = (const float*)d_in[18];
    float* out = (float*)d_out;

    char* ws = (char*)d_ws;
    size_t off = 0;
    auto alloc = [&](size_t bytes) -> char* {
        char* p = ws + off;
        off += (bytes + 255) & ~(size_t)255;
        return p;
    };

    // zero zone (single memset): cnt | denom | gmaxenc | h_g
    const size_t ZZ = (size_t)(NN + 64 + 64 + GG * HH) * 4;
    char* zz = alloc(ZZ);
    int*   cnt     = (int*)zz;
    float* denom   = (float*)(zz + (size_t)NN * 4);
    u32*   gmaxenc = (u32*)(denom + 64);
    float* h_g     = (float*)(gmaxenc + 64);

    int* rowptr = (int*)alloc((NN + 1) * 4);
    int* cur    = (int*)alloc(NN * 4);
    int* bsum   = (int*)alloc(SCAN_B * 4);
    int* colpk  = (int*)alloc((size_t)EE * 4);
    float* gate = (float*)alloc(NN * 4);
    float* wp   = (float*)alloc(260 * 4);
    float* bP   = (float*)alloc(1024 * 4);
    float* pbuf = (float*)alloc((size_t)STB * 512 * 4);
    float* bnsum = (float*)alloc(256 * 4);
    float* bnsq  = (float*)alloc(256 * 4);

    // double-buffered node state: cols 0..255 = a, cols 256..511 = h (fp16)
    f16* ahb[2];
    ahb[0] = (f16*)alloc((size_t)MP * 512 * 2);
    ahb[1] = (f16*)alloc((size_t)MP * 512 * 2);

    f16* Wcat = (f16*)alloc((size_t)256 * KU * 2);
    f16* wP   = (f16*)alloc((size_t)1024 * 512 * 2);
    f16* u    = (f16*)alloc((size_t)MP * KU * 2);

    hipMemsetAsync(zz, 0, ZZ, stream);

    k_pack_W<<<(256 * KU + 255) / 256, 256, 0, stream>>>(W_msg, b_msg, Wcat);
    k_pack_P<<<2048, 256, 0, stream>>>(w_ih, w_hh, wP);
    k_biasP<<<4, 256, 0, stream>>>(b_ih, b_hh, bP);
    k_feat<<<MP, 256, 0, stream>>>(feat, ahb[0]);

    k_count<<<(EE + 255) / 256, 256, 0, stream>>>(dst, cnt);
    k_scan1<<<SCAN_B, 1024, 0, stream>>>(cnt, rowptr, bsum);
    k_scan2<<<1, 64, 0, stream>>>(bsum);
    k_scan3<<<SCAN_B, 1024, 0, stream>>>(rowptr, bsum, cur);
    k_fill<<<(EE + 255) / 256, 256, 0, stream>>>(src, dst, etype, cur, colpk);

    for (int s = 0; s < 5; ++s) {
        f16* ahC = ahb[s & 1];
        f16* ahN = ahb[1 - (s & 1)];
        // per-etype h aggregation (gathers 15 MB hot h, not 60 MB Wh)
        k_aggh<<<MP, 256, 0, stream>>>(ahC, rowptr, colpk, u);
        // a = u * Wcat^T  (same FLOPs as old Wh-GEMM, 1/4 the output)
        gemm_a<<<472, 256, 0, stream>>>(u, Wcat, ahC);
        // fused GRU GEMM + cell -> new h into ahN
        gemm_gruf<<<1880, 256, 0, stream>>>(ahC, wP, bP, ahN);
    }
    f16* ahF = ahb[1];   // s=4 writes into ahb[1]

    k_stats<<<STB, 256, 0, stream>>>(ahF, pbuf);
    k_prep<<<1, 256, 0, stream>>>(pbuf, bn_g, bn_b, gatew, gateb, wp, bnsum, bnsq);
    k_gate<<<235, 256, 0, stream>>>(ahF, wp, n2g, gate, gmaxenc);
    k_expden<<<(NN + 255) / 256, 256, 0, stream>>>(gate, n2g, gmaxenc, denom);
    k_pool<<<MP / 32, 256, 0, stream>>>(ahF, gate, denom, n2g, h_g);
    k_cls<<<GG, 256, 0, stream>>>(h_g, bnsum, bnsq, bn_g, bn_b, W1, b1, W2, b2, out);

    (void)in_sizes; (void)n_in; (void)out_size; (void)ws_size;
}

// Round 15
// 820.049 us; speedup vs baseline: 1.1583x; 1.1583x over previous
//
#include <hip/hip_runtime.h>

#define NN 30000
#define EE 480000
#define HH 256
#define TT 4
#define GG 64
#define CC 10
#define MP 30080   // 235 * 128, padded rows
#define SCAN_B 30  // ceil(NN/1024)
#define STB 120    // stats blocks

typedef unsigned short u16;
typedef unsigned int u32;
typedef _Float16 f16;
typedef f16 half8 __attribute__((ext_vector_type(8)));
typedef f16 half4 __attribute__((ext_vector_type(4)));
typedef float f32x4 __attribute__((ext_vector_type(4)));

// ---------- helpers ----------
__device__ __forceinline__ u32 encf(float x) {       // order-preserving float->uint
    u32 u = __float_as_uint(x);
    return (u & 0x80000000u) ? ~u : (u | 0x80000000u);
}
__device__ __forceinline__ float decf(u32 e) {
    u32 u = (e & 0x80000000u) ? (e ^ 0x80000000u) : ~e;
    return __uint_as_float(u);
}
__device__ __forceinline__ void gl_lds16(const void* g, void* l) {
    __builtin_amdgcn_global_load_lds(
        (const __attribute__((address_space(1))) void*)g,
        (__attribute__((address_space(3))) void*)l, 16, 0, 0);
}
// fast transcendentals (native v_exp_f32 based)
__device__ __forceinline__ float fsig(float x)  { return 1.f / (1.f + __expf(-x)); }
__device__ __forceinline__ float ftanh(float x) { return 1.f - 2.f / (__expf(2.f * x) + 1.f); }
__device__ __forceinline__ float felu(float x)  { return x > 0.f ? x : (__expf(x) - 1.f); }
// XCD-aware swizzle (verified win R11): L%8 = XCD; each XCD gets a contiguous
// band of row-tiles with all 8 col-tiles -> A reuse in its private L2.
__device__ __forceinline__ void xcd_map(int L, int& m0, int& col) {
    int idx = (L & 7) * 235 + (L >> 3);
    m0 = (idx >> 3) * 128;
    col = idx & 7;
}

// ---------- conversion / packing kernels ----------
__global__ void k_convert(const float* __restrict__ in, f16* __restrict__ o, int n) {
    int i = blockIdx.x * 256 + threadIdx.x;
    if (i < n) o[i] = (f16)in[i];
}

// fused-GRU weight wP [8 groups][128 rows][512] (verified R13):
// group g rows: [0,32)=r (K full), [32,64)=i_n (K<256), [64,96)=z (K full), [96,128)=h_n (K>=256)
__global__ void k_pack_P(const float* __restrict__ w_ih, const float* __restrict__ w_hh,
                         f16* __restrict__ o) {
    int i = blockIdx.x * 256 + threadIdx.x;   // over 1024*512
    int p = i >> 9, k = i & 511;
    int g = p >> 7, t = p & 127;
    float v;
    if (t < 32) {
        int row = g * 32 + t;
        v = (k < 256) ? w_ih[row * 256 + k] : w_hh[row * 256 + (k - 256)];
    } else if (t < 64) {
        int row = 512 + g * 32 + (t - 32);
        v = (k < 256) ? w_ih[row * 256 + k] : 0.f;
    } else if (t < 96) {
        int row = 256 + g * 32 + (t - 64);
        v = (k < 256) ? w_ih[row * 256 + k] : w_hh[row * 256 + (k - 256)];
    } else {
        int row = 512 + g * 32 + (t - 96);
        v = (k >= 256) ? w_hh[row * 256 + (k - 256)] : 0.f;
    }
    o[i] = (f16)v;
}

__global__ void k_biasP(const float* __restrict__ b_ih, const float* __restrict__ b_hh,
                        float* __restrict__ bP) {
    int p = threadIdx.x + blockIdx.x * 256;
    if (p >= 1024) return;
    int g = p >> 7, t = p & 127;
    float v;
    if (t < 32)       { int r = g * 32 + t;            v = b_ih[r] + b_hh[r]; }
    else if (t < 64)  { int r = 512 + g * 32 + t - 32; v = b_ih[r]; }
    else if (t < 96)  { int r = 256 + g * 32 + t - 64; v = b_ih[r] + b_hh[r]; }
    else              { int r = 512 + g * 32 + t - 96; v = b_hh[r]; }
    bP[p] = v;
}

// h state -> ah cols 256..511. Padded rows = 0.
__global__ __launch_bounds__(256) void k_feat(const float* __restrict__ feat,
                                              f16* __restrict__ ah) {
    int n = blockIdx.x, c = threadIdx.x;
    float v = (n < NN) ? feat[(size_t)n * HH + c] : 0.f;
    ah[(size_t)n * 512 + 256 + c] = (f16)v;
}

// ---------- CSR build ----------
__global__ void k_count(const int* __restrict__ dst, int* __restrict__ cnt) {
    int e = blockIdx.x * 256 + threadIdx.x;
    if (e < EE) atomicAdd(&cnt[dst[e]], 1);
}

__global__ __launch_bounds__(1024) void k_scan1(const int* __restrict__ cnt,
                                                int* __restrict__ rowptr,
                                                int* __restrict__ bsum) {
    __shared__ int buf[1024];
    int b = blockIdx.x, tid = threadIdx.x;
    int idx = b * 1024 + tid;
    int x = (idx < NN) ? cnt[idx] : 0;
    buf[tid] = x;
    __syncthreads();
    for (int ofs = 1; ofs < 1024; ofs <<= 1) {
        int v = (tid >= ofs) ? buf[tid - ofs] : 0;
        __syncthreads();
        buf[tid] += v;
        __syncthreads();
    }
    if (idx < NN) rowptr[idx] = buf[tid] - x;
    if (tid == 1023) bsum[b] = buf[1023];
}

__global__ void k_scan2(int* __restrict__ bsum) {
    __shared__ int s[SCAN_B];
    int tid = threadIdx.x;
    if (tid < SCAN_B) s[tid] = bsum[tid];
    __syncthreads();
    if (tid == 0) {
        int run = 0;
        for (int i = 0; i < SCAN_B; ++i) { int v = s[i]; s[i] = run; run += v; }
    }
    __syncthreads();
    if (tid < SCAN_B) bsum[tid] = s[tid];
}

__global__ __launch_bounds__(1024) void k_scan3(int* __restrict__ rowptr,
                                                const int* __restrict__ bsum,
                                                int* __restrict__ cur) {
    int b = blockIdx.x, tid = threadIdx.x;
    int idx = b * 1024 + tid;
    if (idx < NN) {
        int v = rowptr[idx] + bsum[b];
        rowptr[idx] = v;
        cur[idx] = v;
    }
    if (idx == 0) rowptr[NN] = EE;
}

__global__ void k_fill(const int* __restrict__ src, const int* __restrict__ dst,
                       const int* __restrict__ et, int* __restrict__ cur,
                       int* __restrict__ colpk) {
    int e = blockIdx.x * 256 + threadIdx.x;
    if (e < EE) {
        int pos = atomicAdd(&cur[dst[e]], 1);
        colpk[pos] = (et[e] << 16) | src[e];
    }
}

// ---------- fp16 MFMA GEMM (Wh), BK=64, XOR-swizzled LDS, fp16 out, XCD-swizzled ----------
__global__ __launch_bounds__(256) void gemm_f16_o16(
    const f16* __restrict__ A, int lda,
    const f16* __restrict__ B, int ldb,
    const float* __restrict__ bias, f16* __restrict__ C, int ldc, int KT) {
    __shared__ f16 sA[8192], sB[8192];
    const int tid = threadIdx.x;
    const int lane = tid & 63;
    const int wv = tid >> 6;
    const int wr = wv >> 1, wc = wv & 1;
    int m0, colt;
    xcd_map(blockIdx.x, m0, colt);
    const int n0 = colt * 128;

    const int ldRow = tid >> 3;
    const int ldK = ((tid & 7) ^ (ldRow & 7)) * 8;
    const f16* aP = A + (size_t)(m0 + ldRow) * lda + ldK;
    const f16* bP = B + (size_t)(n0 + ldRow) * ldb + ldK;
    const size_t rstepA = (size_t)32 * lda;
    const size_t rstepB = (size_t)32 * ldb;

    const int wbyte = (tid & ~63) * 16;
    char* dA = (char*)sA + wbyte;
    char* dB = (char*)sB + wbyte;

    f32x4 acc[4][4];
#pragma unroll
    for (int i = 0; i < 4; i++)
#pragma unroll
        for (int j = 0; j < 4; j++) acc[i][j] = {0.f, 0.f, 0.f, 0.f};

    const int fr = lane & 15;
    const int l7 = lane & 7;
    const int cq = lane >> 4;
    const int p0 = (cq ^ l7) * 8;
    const int p1 = ((cq + 4) ^ l7) * 8;

    for (int kt = 0; kt < KT; ++kt) {
        const int k0 = kt * 64;
        __syncthreads();
        gl_lds16(aP + k0, dA);
        gl_lds16(aP + k0 + rstepA, dA + 4096);
        gl_lds16(aP + k0 + 2 * rstepA, dA + 8192);
        gl_lds16(aP + k0 + 3 * rstepA, dA + 12288);
        gl_lds16(bP + k0, dB);
        gl_lds16(bP + k0 + rstepB, dB + 4096);
        gl_lds16(bP + k0 + 2 * rstepB, dB + 8192);
        gl_lds16(bP + k0 + 3 * rstepB, dB + 12288);
        __syncthreads();

#pragma unroll
        for (int kk = 0; kk < 2; ++kk) {
            const int p = kk ? p1 : p0;
            half8 bh[4];
#pragma unroll
            for (int j = 0; j < 4; j++) {
                int brow = wc * 64 + j * 16 + fr;
                bh[j] = *(const half8*)&sB[brow * 64 + p];
            }
#pragma unroll
            for (int i = 0; i < 4; i++) {
                int arow = wr * 64 + i * 16 + fr;
                half8 ah = *(const half8*)&sA[arow * 64 + p];
#pragma unroll
                for (int j = 0; j < 4; j++)
                    acc[i][j] = __builtin_amdgcn_mfma_f32_16x16x32_f16(ah, bh[j], acc[i][j], 0, 0, 0);
            }
        }
    }

    const int lr = (lane >> 4) * 4;
    const int lc = lane & 15;
#pragma unroll
    for (int j = 0; j < 4; j++) {
        const int col = n0 + wc * 64 + j * 16 + lc;
        const float bj = bias[col];
#pragma unroll
        for (int i = 0; i < 4; i++) {
            const int rb = m0 + wr * 64 + i * 16 + lr;
#pragma unroll
            for (int r = 0; r < 4; r++)
                C[(size_t)(rb + r) * ldc + col] = (f16)(acc[i][j][r] + bj);
        }
    }
}

// ---------- fused GRU GEMM+cell, exchange-free (verified R13) ----------
__global__ __launch_bounds__(256) void gemm_gruf(
    const f16* __restrict__ ahCur,
    const f16* __restrict__ wP,
    const float* __restrict__ bias,
    f16* __restrict__ ahNxt) {
    __shared__ f16 sA[8192], sB[8192];
    const int tid = threadIdx.x;
    const int lane = tid & 63;
    const int wv = tid >> 6;
    int m0, grp;
    xcd_map(blockIdx.x, m0, grp);
    const int n0 = grp * 128;
    const int gcol = grp * 32;

    const int ldRow = tid >> 3;
    const int ldK = ((tid & 7) ^ (ldRow & 7)) * 8;
    const f16* aP = ahCur + (size_t)(m0 + ldRow) * 512 + ldK;
    const f16* bPp = wP + (size_t)(n0 + ldRow) * 512 + ldK;
    const size_t rstep = (size_t)32 * 512;

    const int wbyte = (tid & ~63) * 16;
    char* dA = (char*)sA + wbyte;
    char* dB = (char*)sB + wbyte;

    f32x4 acc[2][8];
#pragma unroll
    for (int i = 0; i < 2; i++)
#pragma unroll
        for (int j = 0; j < 8; j++) acc[i][j] = {0.f, 0.f, 0.f, 0.f};

    const int fr = lane & 15;
    const int l7 = lane & 7;
    const int cq = lane >> 4;
    const int p0 = (cq ^ l7) * 8;
    const int p1 = ((cq + 4) ^ l7) * 8;

#pragma unroll
    for (int hf = 0; hf < 2; ++hf) {
        const int je = hf ? 6 : 2;
#pragma unroll 1
        for (int kt2 = 0; kt2 < 4; ++kt2) {
            const int k0 = (hf * 4 + kt2) * 64;
            __syncthreads();
            gl_lds16(aP + k0, dA);
            gl_lds16(aP + k0 + rstep, dA + 4096);
            gl_lds16(aP + k0 + 2 * rstep, dA + 8192);
            gl_lds16(aP + k0 + 3 * rstep, dA + 12288);
            gl_lds16(bPp + k0, dB);
            gl_lds16(bPp + k0 + rstep, dB + 4096);
            gl_lds16(bPp + k0 + 2 * rstep, dB + 8192);
            gl_lds16(bPp + k0 + 3 * rstep, dB + 12288);
            __syncthreads();

#pragma unroll
            for (int kk = 0; kk < 2; ++kk) {
                const int p = kk ? p1 : p0;
                const half8 a0 = *(const half8*)&sA[(wv * 32 + fr) * 64 + p];
                const half8 a1 = *(const half8*)&sA[(wv * 32 + 16 + fr) * 64 + p];
                half8 b;
                b = *(const half8*)&sB[(0 * 16 + fr) * 64 + p];
                acc[0][0] = __builtin_amdgcn_mfma_f32_16x16x32_f16(a0, b, acc[0][0], 0, 0, 0);
                acc[1][0] = __builtin_amdgcn_mfma_f32_16x16x32_f16(a1, b, acc[1][0], 0, 0, 0);
                b = *(const half8*)&sB[(1 * 16 + fr) * 64 + p];
                acc[0][1] = __builtin_amdgcn_mfma_f32_16x16x32_f16(a0, b, acc[0][1], 0, 0, 0);
                acc[1][1] = __builtin_amdgcn_mfma_f32_16x16x32_f16(a1, b, acc[1][1], 0, 0, 0);
                b = *(const half8*)&sB[(4 * 16 + fr) * 64 + p];
                acc[0][4] = __builtin_amdgcn_mfma_f32_16x16x32_f16(a0, b, acc[0][4], 0, 0, 0);
                acc[1][4] = __builtin_amdgcn_mfma_f32_16x16x32_f16(a1, b, acc[1][4], 0, 0, 0);
                b = *(const half8*)&sB[(5 * 16 + fr) * 64 + p];
                acc[0][5] = __builtin_amdgcn_mfma_f32_16x16x32_f16(a0, b, acc[0][5], 0, 0, 0);
                acc[1][5] = __builtin_amdgcn_mfma_f32_16x16x32_f16(a1, b, acc[1][5], 0, 0, 0);
                b = *(const half8*)&sB[(je * 16 + fr) * 64 + p];
                acc[0][je] = __builtin_amdgcn_mfma_f32_16x16x32_f16(a0, b, acc[0][je], 0, 0, 0);
                acc[1][je] = __builtin_amdgcn_mfma_f32_16x16x32_f16(a1, b, acc[1][je], 0, 0, 0);
                b = *(const half8*)&sB[((je + 1) * 16 + fr) * 64 + p];
                acc[0][je + 1] = __builtin_amdgcn_mfma_f32_16x16x32_f16(a0, b, acc[0][je + 1], 0, 0, 0);
                acc[1][je + 1] = __builtin_amdgcn_mfma_f32_16x16x32_f16(a1, b, acc[1][je + 1], 0, 0, 0);
            }
        }
    }

    const int lr = (lane >> 4) * 4;
    const int lc = lane & 15;
#pragma unroll
    for (int jj = 0; jj < 2; ++jj) {
        const int c32 = jj * 16 + lc;
        const float br = bias[n0 + c32];
        const float bi = bias[n0 + 32 + c32];
        const float bz = bias[n0 + 64 + c32];
        const float bn = bias[n0 + 96 + c32];
#pragma unroll
        for (int i = 0; i < 2; ++i) {
#pragma unroll
            for (int r = 0; r < 4; ++r) {
                const int n = m0 + wv * 32 + i * 16 + lr + r;
                float rv = acc[i][jj][r] + br;
                float iv = acc[i][jj + 2][r] + bi;
                float zv = acc[i][jj + 4][r] + bz;
                float nv = acc[i][jj + 6][r] + bn;
                float rr = fsig(rv);
                float zz = fsig(zv);
                float nn2 = ftanh(iv + rr * nv);
                size_t hidx = (size_t)n * 512 + 256 + gcol + c32;
                float hv = (float)ahCur[hidx];
                ahNxt[hidx] = (f16)((1.f - zz) * nn2 + zz * hv);
            }
        }
    }
}

// ---------- per-dst aggregation (pull via CSR, latency-hidden) -> ah cols 0..255 ----------
__global__ __launch_bounds__(256) void k_agg(const f16* __restrict__ Wh,
                                             const int* __restrict__ rowptr,
                                             const int* __restrict__ colpk,
                                             f16* __restrict__ ah) {
    __shared__ int spk[256];
    __shared__ float4 sacc[3][64];
    const int n = blockIdx.x;
    const int tid = threadIdx.x;
    const int col4 = tid & 63;
    const int strip = tid >> 6;
    float4 acc = {0.f, 0.f, 0.f, 0.f};

    if (n < NN) {
        const int e0 = rowptr[n], e1 = rowptr[n + 1];
        for (int base = e0; base < e1; base += 256) {
            const int chunk = min(256, e1 - base);
            __syncthreads();
            if (tid < chunk) spk[tid] = colpk[base + tid];
            __syncthreads();
            int i = strip;
            for (; i + 4 < chunk; i += 8) {
                const int pk0 = spk[i], pk1 = spk[i + 4];
                const half4 v0 = *(const half4*)&Wh[(size_t)(pk0 & 0xFFFF) * 1024 + (pk0 >> 16) * 256 + col4 * 4];
                const half4 v1 = *(const half4*)&Wh[(size_t)(pk1 & 0xFFFF) * 1024 + (pk1 >> 16) * 256 + col4 * 4];
                acc.x += (float)v0.x + (float)v1.x;
                acc.y += (float)v0.y + (float)v1.y;
                acc.z += (float)v0.z + (float)v1.z;
                acc.w += (float)v0.w + (float)v1.w;
            }
            for (; i < chunk; i += 4) {
                const int pk = spk[i];
                const half4 v = *(const half4*)&Wh[(size_t)(pk & 0xFFFF) * 1024 + (pk >> 16) * 256 + col4 * 4];
                acc.x += (float)v.x;
                acc.y += (float)v.y;
                acc.z += (float)v.z;
                acc.w += (float)v.w;
            }
        }
    }
    if (strip) sacc[strip - 1][col4] = acc;
    __syncthreads();
    if (strip == 0 && n < NN) {
        const float4 t0 = sacc[0][col4], t1 = sacc[1][col4], t2 = sacc[2][col4];
        half4 o;
        o.x = (f16)(acc.x + t0.x + t1.x + t2.x);
        o.y = (f16)(acc.y + t0.y + t1.y + t2.y);
        o.z = (f16)(acc.z + t0.z + t1.z + t2.z);
        o.w = (f16)(acc.w + t0.w + t1.w + t2.w);
        *(half4*)&ah[(size_t)n * 512 + col4 * 4] = o;
    }
}

// ---------- BN stats over elu(h): per-block partials, NO atomics ----------
__global__ __launch_bounds__(256) void k_stats(const f16* __restrict__ ah,
                                               float* __restrict__ pbuf) {
    __shared__ float4 ssum[3][64], ssq[3][64];
    int tid = threadIdx.x, lane = tid & 63, w = tid >> 6;
    int c4 = lane * 4;
    float4 s = {0.f, 0.f, 0.f, 0.f}, q = {0.f, 0.f, 0.f, 0.f};
    for (int n = blockIdx.x * 4 + w; n < NN; n += STB * 4) {
        half4 v = *(const half4*)&ah[(size_t)n * 512 + 256 + c4];
        float ex = felu((float)v.x), ey = felu((float)v.y);
        float ez = felu((float)v.z), ew = felu((float)v.w);
        s.x += ex; s.y += ey; s.z += ez; s.w += ew;
        q.x += ex * ex; q.y += ey * ey; q.z += ez * ez; q.w += ew * ew;
    }
    if (w) { ssum[w - 1][lane] = s; ssq[w - 1][lane] = q; }
    __syncthreads();
    if (w == 0) {
#pragma unroll
        for (int k = 0; k < 3; ++k) {
            float4 a = ssum[k][lane], b = ssq[k][lane];
            s.x += a.x; s.y += a.y; s.z += a.z; s.w += a.w;
            q.x += b.x; q.y += b.y; q.z += b.z; q.w += b.w;
        }
        *(float4*)&pbuf[blockIdx.x * 512 + c4] = s;
        *(float4*)&pbuf[blockIdx.x * 512 + 256 + c4] = q;
    }
}

// ---------- reduce partials + fold BN affine into gate weights ----------
__global__ __launch_bounds__(256) void k_prep(const float* __restrict__ pbuf,
                                              const float* __restrict__ gamma,
                                              const float* __restrict__ beta,
                                              const float* __restrict__ gate_w,
                                              const float* __restrict__ gate_b,
                                              float* __restrict__ wp,
                                              float* __restrict__ bnsum,
                                              float* __restrict__ bnsq) {
    __shared__ float red[256];
    int c = threadIdx.x;
    float s = 0.f, q = 0.f;
    for (int b = 0; b < STB; ++b) {
        s += pbuf[b * 512 + c];
        q += pbuf[b * 512 + 256 + c];
    }
    bnsum[c] = s;
    bnsq[c] = q;
    float mu = s * (1.f / NN);
    float var = q * (1.f / NN) - mu * mu;
    float rs = rsqrtf(var + 1e-5f);
    float gm = gamma[c], w = gate_w[c];
    wp[c] = rs * gm * w;
    red[c] = (beta[c] - mu * rs * gm) * w;
    __syncthreads();
    for (int st = 128; st > 0; st >>= 1) {
        if (c < st) red[c] += red[c + st];
        __syncthreads();
    }
    if (c == 0) wp[256] = red[0] + gate_b[0];
}

// ---------- gate score: elu on the fly, wave dots, LDS-staged segment max ----------
__global__ __launch_bounds__(256) void k_gate(const f16* __restrict__ ah,
                                              const float* __restrict__ wp,
                                              const int* __restrict__ n2g,
                                              float* __restrict__ gate,
                                              u32* __restrict__ gmaxenc) {
    __shared__ u32 smax[64];
    int tid = threadIdx.x;
    if (tid < 64) smax[tid] = 0;
    __syncthreads();
    int lane = tid & 63, wv = tid >> 6;
    int base = blockIdx.x * 128 + wv * 32;
    float4 w = ((const float4*)wp)[lane];
    float wc = wp[256];
    for (int k = 0; k < 32; ++k) {
        int n = base + k;
        if (n >= NN) break;
        half4 v = *(const half4*)&ah[(size_t)n * 512 + 256 + lane * 4];
        float s = felu((float)v.x) * w.x + felu((float)v.y) * w.y +
                  felu((float)v.z) * w.z + felu((float)v.w) * w.w;
#pragma unroll
        for (int off = 32; off; off >>= 1) s += __shfl_down(s, off);
        if (lane == 0) {
            float gt = s + wc;
            gate[n] = gt;
            atomicMax(&smax[n2g[n]], encf(gt));
        }
    }
    __syncthreads();
    if (tid < 64 && smax[tid]) atomicMax(&gmaxenc[tid], smax[tid]);
}

// ---------- exp + denom (LDS-staged segment sum) ----------
__global__ void k_expden(float* __restrict__ gate,
                         const int* __restrict__ n2g,
                         const u32* __restrict__ gmaxenc,
                         float* __restrict__ denom) {
    __shared__ float ssum[64];
    int tid = threadIdx.x;
    if (tid < 64) ssum[tid] = 0.f;
    __syncthreads();
    int n = blockIdx.x * 256 + tid;
    if (n < NN) {
        int g = n2g[n];
        float e = __expf(gate[n] - decf(gmaxenc[g]));
        gate[n] = e;
        atomicAdd(&ssum[g], e);
    }
    __syncthreads();
    if (tid < 64 && ssum[tid] != 0.f) atomicAdd(&denom[tid], ssum[tid]);
}

// ---------- attention pooling, elu on the fly (n2g sorted; flush on change) ----------
__global__ __launch_bounds__(256) void k_pool(const f16* __restrict__ ah,
                                              const float* __restrict__ gate,
                                              const float* __restrict__ denom,
                                              const int* __restrict__ n2g,
                                              float* __restrict__ h_g) {
    int c = threadIdx.x;
    int r0 = blockIdx.x * 32, r1 = min(r0 + 32, NN);
    int gcur = -1;
    float accv = 0.f, inv = 0.f;
    for (int n = r0; n < r1; ++n) {
        int g = n2g[n];
        if (g != gcur) {
            if (gcur >= 0) atomicAdd(&h_g[gcur * HH + c], accv);
            gcur = g;
            accv = 0.f;
            inv = 1.f / denom[g];
        }
        float x = felu((float)ah[(size_t)n * 512 + 256 + c]);
        accv += gate[n] * inv * x;
    }
    if (gcur >= 0) atomicAdd(&h_g[gcur * HH + c], accv);
}

// ---------- classifier (applies BN affine to pooled vector) ----------
__global__ __launch_bounds__(256) void k_cls(const float* __restrict__ h_g,
                                             const float* __restrict__ bnsum,
                                             const float* __restrict__ bnsq,
                                             const float* __restrict__ gamma,
                                             const float* __restrict__ beta,
                                             const float* __restrict__ W1,
                                             const float* __restrict__ b1,
                                             const float* __restrict__ W2,
                                             const float* __restrict__ b2,
                                             float* __restrict__ out) {
    __shared__ float hg[256];
    __shared__ float x1[128];
    int g = blockIdx.x, tid = threadIdx.x;
    float mu = bnsum[tid] * (1.f / NN);
    float var = bnsq[tid] * (1.f / NN) - mu * mu;
    hg[tid] = (h_g[g * HH + tid] - mu) * rsqrtf(var + 1e-5f) * gamma[tid] + beta[tid];
    __syncthreads();
    if (tid < 128) {
        const float* w = W1 + tid * 256;
        float s = b1[tid];
#pragma unroll 8
        for (int c = 0; c < 256; ++c) s += hg[c] * w[c];
        x1[tid] = fmaxf(s, 0.f);
    }
    __syncthreads();
    if (tid < 10) {
        const float* w = W2 + tid * 128;
        float s = b2[tid];
        for (int j = 0; j < 128; ++j) s += x1[j] * w[j];
        out[g * CC + tid] = s;
    }
}

// =======================================================================
extern "C" void kernel_launch(void* const* d_in, const int* in_sizes, int n_in,
                              void* d_out, int out_size, void* d_ws, size_t ws_size,
                              hipStream_t stream) {
    const float* feat  = (const float*)d_in[0];
    const int*   src   = (const int*)d_in[1];
    const int*   dst   = (const int*)d_in[2];
    const int*   etype = (const int*)d_in[3];
    const int*   n2g   = (const int*)d_in[4];
    const float* W_msg = (const float*)d_in[5];
    const float* b_msg = (const float*)d_in[6];
    const float* w_ih  = (const float*)d_in[7];
    const float* w_hh  = (const float*)d_in[8];
    const float* b_ih  = (const float*)d_in[9];
    const float* b_hh  = (const float*)d_in[10];
    const float* bn_g  = (const float*)d_in[11];
    const float* bn_b  = (const float*)d_in[12];
    const float* gatew = (const float*)d_in[13];
    const float* gateb = (const float*)d_in[14];
    const float* W1    = (const float*)d_in[15];
    const float* b1    = (const float*)d_in[16];
    const float* W2    = (const float*)d_in[17];
    const float* b2    = (const float*)d_in[18];
    float* out = (float*)d_out;

    char* ws = (char*)d_ws;
    size_t off = 0;
    auto alloc = [&](size_t bytes) -> char* {
        char* p = ws + off;
        off += (bytes + 255) & ~(size_t)255;
        return p;
    };

    // zero zone (single memset): cnt | denom | gmaxenc | h_g
    const size_t ZZ = (size_t)(NN + 64 + 64 + GG * HH) * 4;
    char* zz = alloc(ZZ);
    int*   cnt     = (int*)zz;
    float* denom   = (float*)(zz + (size_t)NN * 4);
    u32*   gmaxenc = (u32*)(denom + 64);
    float* h_g     = (float*)(gmaxenc + 64);

    int* rowptr = (int*)alloc((NN + 1) * 4);
    int* cur    = (int*)alloc(NN * 4);
    int* bsum   = (int*)alloc(SCAN_B * 4);
    int* colpk  = (int*)alloc((size_t)EE * 4);
    float* gate = (float*)alloc(NN * 4);
    float* wp   = (float*)alloc(260 * 4);
    float* bP   = (float*)alloc(1024 * 4);
    float* pbuf = (float*)alloc((size_t)STB * 512 * 4);
    float* bnsum = (float*)alloc(256 * 4);
    float* bnsq  = (float*)alloc(256 * 4);

    // double-buffered node state: cols 0..255 = a, cols 256..511 = h (fp16)
    f16* ahb[2];
    ahb[0] = (f16*)alloc((size_t)MP * 512 * 2);
    ahb[1] = (f16*)alloc((size_t)MP * 512 * 2);

    f16* wmsg = (f16*)alloc((size_t)1024 * 256 * 2);
    f16* wP   = (f16*)alloc((size_t)1024 * 512 * 2);
    f16* Wh   = (f16*)alloc((size_t)MP * 1024 * 2);

    hipMemsetAsync(zz, 0, ZZ, stream);

    k_convert<<<1024, 256, 0, stream>>>(W_msg, wmsg, 1024 * 256);
    k_pack_P<<<2048, 256, 0, stream>>>(w_ih, w_hh, wP);
    k_biasP<<<4, 256, 0, stream>>>(b_ih, b_hh, bP);
    k_feat<<<MP, 256, 0, stream>>>(feat, ahb[0]);

    k_count<<<(EE + 255) / 256, 256, 0, stream>>>(dst, cnt);
    k_scan1<<<SCAN_B, 1024, 0, stream>>>(cnt, rowptr, bsum);
    k_scan2<<<1, 64, 0, stream>>>(bsum);
    k_scan3<<<SCAN_B, 1024, 0, stream>>>(rowptr, bsum, cur);
    k_fill<<<(EE + 255) / 256, 256, 0, stream>>>(src, dst, etype, cur, colpk);

    for (int s = 0; s < 5; ++s) {
        f16* ahC = ahb[s & 1];
        f16* ahN = ahb[1 - (s & 1)];
        // Wh = h * W_msg^T  [MP x 1024] fp16 (K=256 -> KT=4), XCD-swizzled
        gemm_f16_o16<<<1880, 256, 0, stream>>>(
            ahC + 256, 512, wmsg, 256, b_msg, Wh, 1024, 4);
        k_agg<<<MP, 256, 0, stream>>>(Wh, rowptr, colpk, ahC);
        // fused GRU GEMM + cell -> new h into ahN
        gemm_gruf<<<1880, 256, 0, stream>>>(ahC, wP, bP, ahN);
    }
    f16* ahF = ahb[1];   // s=4 writes into ahb[1]

    k_stats<<<STB, 256, 0, stream>>>(ahF, pbuf);
    k_prep<<<1, 256, 0, stream>>>(pbuf, bn_g, bn_b, gatew, gateb, wp, bnsum, bnsq);
    k_gate<<<235, 256, 0, stream>>>(ahF, wp, n2g, gate, gmaxenc);
    k_expden<<<(NN + 255) / 256, 256, 0, stream>>>(gate, n2g, gmaxenc, denom);
    k_pool<<<MP / 32, 256, 0, stream>>>(ahF, gate, denom, n2g, h_g);
    k_cls<<<GG, 256, 0, stream>>>(h_g, bnsum, bnsq, bn_g, bn_b, W1, b1, W2, b2, out);

    (void)in_sizes; (void)n_in; (void)out_size; (void)ws_size;
}